// Round 2
// baseline (2720.098 us; speedup 1.0000x reference)
//
#include <hip/hip_runtime.h>
#include <math.h>

#define T 2048
#define H 4096
#define NQ 32
#define NKV 8
#define HD 128
#define VD 96
#define WIN 1024
#define NE 8
#define FF 1408
#define TOPK 2

typedef __bf16 bf16x8 __attribute__((ext_vector_type(8)));
typedef float f32x4 __attribute__((ext_vector_type(4)));

__device__ __forceinline__ unsigned short f2bf(float f) {
  union { float f; unsigned u; } v; v.f = f;
  unsigned r = v.u + 0x7fffu + ((v.u >> 16) & 1u);
  return (unsigned short)(r >> 16);
}
__device__ __forceinline__ float bf2f(unsigned short h) {
  union { unsigned u; float f; } v; v.u = ((unsigned)h) << 16;
  return v.f;
}

__device__ __forceinline__ f32x4 mfma16(bf16x8 a, bf16x8 b, f32x4 c) {
  return __builtin_amdgcn_mfma_f32_16x16x32_bf16(a, b, c, 0, 0, 0);
}
__device__ __forceinline__ f32x4 fzero4() { f32x4 z = {0.f, 0.f, 0.f, 0.f}; return z; }

// ---------------------------------------------------------------------------
// Generic bf16-MFMA GEMM: C[M,N] = A[M,K] @ B[K,N].
// SPLIT==1: compensated split-bf16 (A=Ah+Al, B=Bh+Bl; hi*hi+hi*lo+lo*hi)
//           giving ~f32 accuracy at 3x MFMA cost.
// EPI==1: C = acc + res (residual add).
// e_off != null: per-expert mode, blockIdx.z = expert.
// row_idx != null: A row gather.
// ---------------------------------------------------------------------------
template<int EPI, int SPLIT>
__global__ __launch_bounds__(256) void gemm_bf16(
    const float* __restrict__ A, int lda,
    const float* __restrict__ B, int ldb, long long strideB,
    float* __restrict__ C, int ldc,
    const float* __restrict__ res,
    const int* __restrict__ row_idx,
    const int* __restrict__ e_off,
    int M, int N, int K)
{
  __shared__ __align__(16) unsigned short As[SPLIT ? 2 : 1][128][40];
  __shared__ __align__(16) unsigned short Bs[SPLIT ? 2 : 1][128][40];

  int rowbase = 0, Mloc = M;
  if (e_off) {
    int e = blockIdx.z;
    rowbase = e_off[e];
    Mloc = e_off[e + 1] - rowbase;
    B += strideB * (long long)e;
  }
  int mtile = blockIdx.y * 128;
  if (mtile >= Mloc) return;
  int n0 = blockIdx.x * 128;

  int tid = threadIdx.x;
  int lane = tid & 63;
  int wave = tid >> 6;
  int g = lane >> 4, cc = lane & 15;
  int wrow = (wave >> 1) * 64, wcol = (wave & 1) * 64;

  f32x4 acc[4][4];
#pragma unroll
  for (int m = 0; m < 4; ++m)
#pragma unroll
    for (int n = 0; n < 4; ++n) acc[m][n] = fzero4();

  int nK = K >> 5;
  for (int kt = 0; kt < nK; ++kt) {
    int k0 = kt << 5;
    __syncthreads();
    // --- stage A: 128 rows x 32 k
#pragma unroll
    for (int i = 0; i < 4; ++i) {
      int f = tid + i * 256;
      int row = f >> 3;
      int kc = (f & 7) << 2;
      int grow = mtile + row;
      float4 v = make_float4(0.f, 0.f, 0.f, 0.f);
      if (grow < Mloc) {
        int arow = rowbase + grow;
        if (row_idx) arow = row_idx[arow];
        v = *(const float4*)(A + (size_t)arow * lda + k0 + kc);
      }
      ushort4 uh;
      uh.x = f2bf(v.x); uh.y = f2bf(v.y); uh.z = f2bf(v.z); uh.w = f2bf(v.w);
      *(ushort4*)&As[0][row][kc] = uh;
      if (SPLIT) {
        ushort4 ul;
        ul.x = f2bf(v.x - bf2f(uh.x)); ul.y = f2bf(v.y - bf2f(uh.y));
        ul.z = f2bf(v.z - bf2f(uh.z)); ul.w = f2bf(v.w - bf2f(uh.w));
        *(ushort4*)&As[1][row][kc] = ul;
      }
    }
    // --- stage B transposed: Bs[n][k] <- B[k0+k][n0+n]
#pragma unroll
    for (int i = 0; i < 4; ++i) {
      int f = tid + i * 256;
      int nn = f & 127;
      int kq = f >> 7;  // 0..7, 4 k each
      const float* bp = B + (size_t)(k0 + (kq << 2)) * ldb + n0 + nn;
      float b0 = bp[0], b1 = bp[(size_t)ldb], b2 = bp[2 * (size_t)ldb], b3 = bp[3 * (size_t)ldb];
      ushort4 uh;
      uh.x = f2bf(b0); uh.y = f2bf(b1); uh.z = f2bf(b2); uh.w = f2bf(b3);
      *(ushort4*)&Bs[0][nn][kq << 2] = uh;
      if (SPLIT) {
        ushort4 ul;
        ul.x = f2bf(b0 - bf2f(uh.x)); ul.y = f2bf(b1 - bf2f(uh.y));
        ul.z = f2bf(b2 - bf2f(uh.z)); ul.w = f2bf(b3 - bf2f(uh.w));
        *(ushort4*)&Bs[1][nn][kq << 2] = ul;
      }
    }
    __syncthreads();
    bf16x8 avh[4], bvh[4], avl[4], bvl[4];
#pragma unroll
    for (int m = 0; m < 4; ++m) {
      avh[m] = *(const bf16x8*)&As[0][wrow + m * 16 + cc][g * 8];
      if (SPLIT) avl[m] = *(const bf16x8*)&As[1][wrow + m * 16 + cc][g * 8];
    }
#pragma unroll
    for (int n = 0; n < 4; ++n) {
      bvh[n] = *(const bf16x8*)&Bs[0][wcol + n * 16 + cc][g * 8];
      if (SPLIT) bvl[n] = *(const bf16x8*)&Bs[1][wcol + n * 16 + cc][g * 8];
    }
#pragma unroll
    for (int m = 0; m < 4; ++m)
#pragma unroll
      for (int n = 0; n < 4; ++n) {
        acc[m][n] = mfma16(avh[m], bvh[n], acc[m][n]);
        if (SPLIT) {
          acc[m][n] = mfma16(avh[m], bvl[n], acc[m][n]);
          acc[m][n] = mfma16(avl[m], bvh[n], acc[m][n]);
        }
      }
  }

#pragma unroll
  for (int m = 0; m < 4; ++m) {
    int rl = wrow + m * 16 + g * 4;
#pragma unroll
    for (int n = 0; n < 4; ++n) {
      int col = n0 + wcol + n * 16 + cc;
#pragma unroll
      for (int r = 0; r < 4; ++r) {
        int grow = mtile + rl + r;
        if (grow < Mloc) {
          size_t off = (size_t)(rowbase + grow) * ldc + col;
          float vv = acc[m][n][r];
          if (EPI == 1) vv += res[off];
          C[off] = vv;
        }
      }
    }
  }
}

// ---------------------------------------------------------------------------
// RMSNorm: one block per token, H=4096.
// ---------------------------------------------------------------------------
__global__ __launch_bounds__(256) void rmsnorm_kernel(const float* __restrict__ in,
    const float* __restrict__ w, float* __restrict__ out)
{
  int t = blockIdx.x;
  int tid = threadIdx.x;
  const float4* rp = (const float4*)(in + (size_t)t * H);
  const float4* wp = (const float4*)w;
  float4* op = (float4*)(out + (size_t)t * H);
  float4 vv[4];
  float ss = 0.f;
#pragma unroll
  for (int i = 0; i < 4; ++i) {
    vv[i] = rp[tid + i * 256];
    ss += vv[i].x * vv[i].x + vv[i].y * vv[i].y + vv[i].z * vv[i].z + vv[i].w * vv[i].w;
  }
#pragma unroll
  for (int off = 32; off > 0; off >>= 1) ss += __shfl_xor(ss, off);
  __shared__ float red[4];
  if ((tid & 63) == 0) red[tid >> 6] = ss;
  __syncthreads();
  float tot = red[0] + red[1] + red[2] + red[3];
  float rs = rsqrtf(tot * (1.f / H) + 1e-6f);
#pragma unroll
  for (int i = 0; i < 4; ++i) {
    float4 x = vv[i];
    float4 ww = wp[tid + i * 256];
    float4 o;
    o.x = x.x * rs * ww.x; o.y = x.y * rs * ww.y;
    o.z = x.z * rs * ww.z; o.w = x.w * rs * ww.w;
    op[tid + i * 256] = o;
  }
}

// ---------------------------------------------------------------------------
// RoPE in place on q (T,NQ,HD) and k (T,NKV,HD). half-split style.
// ---------------------------------------------------------------------------
__global__ __launch_bounds__(256) void rope_kernel(const int* __restrict__ pos,
    float* __restrict__ q, float* __restrict__ kbuf)
{
  int t = blockIdx.x;
  float p = (float)pos[t];
  for (int idx = threadIdx.x; idx < (NQ + NKV) * 64; idx += 256) {
    float* base;
    int d;
    if (idx < NQ * 64) {
      int h = idx >> 6; d = idx & 63;
      base = q + (size_t)t * (NQ * HD) + h * HD;
    } else {
      int j = idx - NQ * 64;
      int h = j >> 6; d = j & 63;
      base = kbuf + (size_t)t * (NKV * HD) + h * HD;
    }
    float inv = exp2f(-19.931568569324174f * (float)(2 * d) * (1.0f / 128.0f));
    float ang = p * inv;
    float sn = sinf(ang), cs = cosf(ang);
    float x1 = base[d], x2 = base[d + 64];
    base[d] = x1 * cs - x2 * sn;
    base[d + 64] = x2 * cs + x1 * sn;
  }
}

// ---------------------------------------------------------------------------
// Flash attention, sliding window + sink. One block = (64 queries, 1 head).
// Split-bf16 (3-pass MFMA) on both QK^T and PV for ~f32 accuracy.
// ---------------------------------------------------------------------------
__global__ __launch_bounds__(256) void attn_kernel(
    const float* __restrict__ q, const float* __restrict__ kbuf,
    const float* __restrict__ vbuf, const float* __restrict__ sink,
    const int* __restrict__ pos, float* __restrict__ out)
{
  __shared__ __align__(16) unsigned short Qs[2][64][136];
  __shared__ __align__(16) unsigned short Ks[2][32][136];
  __shared__ __align__(16) unsigned short Vt[2][96][40];   // [vd][key]
  __shared__ __align__(16) unsigned short Ps[2][4][16][40];
  __shared__ int posq[64];
  __shared__ int posk[32];

  const float SCALE = 0.08838834764831843f;  // 128^-0.5
  int qs = blockIdx.x * 64;
  int head = blockIdx.y;
  int kvh = head >> 2;  // rep = NQ/NKV = 4
  int tid = threadIdx.x;
  int lane = tid & 63, wave = tid >> 6;
  int g = lane >> 4, cc = lane & 15;
  int wq0 = wave * 16;

#pragma unroll
  for (int i = 0; i < 8; ++i) {
    int f = tid + i * 256;
    int row = f >> 5, dc = (f & 31) << 2;
    float4 v = *(const float4*)(q + (size_t)(qs + row) * (NQ * HD) + head * HD + dc);
    ushort4 uh, ul;
    uh.x = f2bf(v.x); uh.y = f2bf(v.y); uh.z = f2bf(v.z); uh.w = f2bf(v.w);
    ul.x = f2bf(v.x - bf2f(uh.x)); ul.y = f2bf(v.y - bf2f(uh.y));
    ul.z = f2bf(v.z - bf2f(uh.z)); ul.w = f2bf(v.w - bf2f(uh.w));
    *(ushort4*)&Qs[0][row][dc] = uh;
    *(ushort4*)&Qs[1][row][dc] = ul;
  }
  if (tid < 64) posq[tid] = pos[qs + tid];

  float m_r[4], l_r[4];
  f32x4 acc_o[6];
#pragma unroll
  for (int r = 0; r < 4; ++r) { m_r[r] = -__builtin_huge_valf(); l_r[r] = 0.f; }
#pragma unroll
  for (int n = 0; n < 6; ++n) acc_o[n] = fzero4();

  int kstart = qs - (WIN - 1);
  if (kstart < 0) kstart = 0;
  kstart &= ~31;
  int kend = qs + 63;

  for (int k0 = kstart; k0 <= kend; k0 += 32) {
    __syncthreads();
#pragma unroll
    for (int i = 0; i < 4; ++i) {
      int f = tid + i * 256;
      int row = f >> 5, dc = (f & 31) << 2;
      float4 v = *(const float4*)(kbuf + (size_t)(k0 + row) * (NKV * HD) + kvh * HD + dc);
      ushort4 uh, ul;
      uh.x = f2bf(v.x); uh.y = f2bf(v.y); uh.z = f2bf(v.z); uh.w = f2bf(v.w);
      ul.x = f2bf(v.x - bf2f(uh.x)); ul.y = f2bf(v.y - bf2f(uh.y));
      ul.z = f2bf(v.z - bf2f(uh.z)); ul.w = f2bf(v.w - bf2f(uh.w));
      *(ushort4*)&Ks[0][row][dc] = uh;
      *(ushort4*)&Ks[1][row][dc] = ul;
    }
#pragma unroll
    for (int i = 0; i < 3; ++i) {
      int f = tid + i * 256;
      int row = f / 24, c4 = (f % 24) << 2;
      float4 v = *(const float4*)(vbuf + (size_t)(k0 + row) * (NKV * VD) + kvh * VD + c4);
      unsigned short h0 = f2bf(v.x), h1 = f2bf(v.y), h2 = f2bf(v.z), h3 = f2bf(v.w);
      Vt[0][c4 + 0][row] = h0; Vt[1][c4 + 0][row] = f2bf(v.x - bf2f(h0));
      Vt[0][c4 + 1][row] = h1; Vt[1][c4 + 1][row] = f2bf(v.y - bf2f(h1));
      Vt[0][c4 + 2][row] = h2; Vt[1][c4 + 2][row] = f2bf(v.z - bf2f(h2));
      Vt[0][c4 + 3][row] = h3; Vt[1][c4 + 3][row] = f2bf(v.w - bf2f(h3));
    }
    if (tid < 32) posk[tid] = pos[k0 + tid];
    __syncthreads();

    // S = Q K^T for this wave's 16 rows x 32 keys (split-bf16, 3 passes)
    bf16x8 aqh[4], aql[4];
#pragma unroll
    for (int kk = 0; kk < 4; ++kk) {
      aqh[kk] = *(const bf16x8*)&Qs[0][wq0 + cc][kk * 32 + g * 8];
      aql[kk] = *(const bf16x8*)&Qs[1][wq0 + cc][kk * 32 + g * 8];
    }
    f32x4 sacc[2];
    sacc[0] = fzero4(); sacc[1] = fzero4();
#pragma unroll
    for (int kb = 0; kb < 2; ++kb)
#pragma unroll
      for (int kk = 0; kk < 4; ++kk) {
        bf16x8 bh = *(const bf16x8*)&Ks[0][kb * 16 + cc][kk * 32 + g * 8];
        bf16x8 bl = *(const bf16x8*)&Ks[1][kb * 16 + cc][kk * 32 + g * 8];
        sacc[kb] = mfma16(aqh[kk], bh, sacc[kb]);
        sacc[kb] = mfma16(aqh[kk], bl, sacc[kb]);
        sacc[kb] = mfma16(aql[kk], bh, sacc[kb]);
      }

    int j0 = posk[cc], j1 = posk[16 + cc];
#pragma unroll
    for (int r = 0; r < 4; ++r) {
      int irow = posq[wq0 + g * 4 + r];
      float s0 = sacc[0][r] * SCALE;
      float s1 = sacc[1][r] * SCALE;
      bool ok0 = (j0 <= irow) && (irow - j0 < WIN);
      bool ok1 = (j1 <= irow) && (irow - j1 < WIN);
      if (!ok0) s0 = -1e30f;
      if (!ok1) s1 = -1e30f;
      float rm = fmaxf(s0, s1);
#pragma unroll
      for (int off = 1; off < 16; off <<= 1) rm = fmaxf(rm, __shfl_xor(rm, off));
      float mn = fmaxf(m_r[r], rm);
      float p0 = ok0 ? __expf(s0 - mn) : 0.f;
      float p1 = ok1 ? __expf(s1 - mn) : 0.f;
      float rs = p0 + p1;
#pragma unroll
      for (int off = 1; off < 16; off <<= 1) rs += __shfl_xor(rs, off);
      float alpha = __expf(m_r[r] - mn);  // exp(-inf)=0 on first tile
      l_r[r] = l_r[r] * alpha + rs;
      m_r[r] = mn;
#pragma unroll
      for (int n = 0; n < 6; ++n) acc_o[n][r] *= alpha;
      unsigned short p0h = f2bf(p0), p1h = f2bf(p1);
      Ps[0][wave][g * 4 + r][cc] = p0h;
      Ps[1][wave][g * 4 + r][cc] = f2bf(p0 - bf2f(p0h));
      Ps[0][wave][g * 4 + r][16 + cc] = p1h;
      Ps[1][wave][g * 4 + r][16 + cc] = f2bf(p1 - bf2f(p1h));
    }
    // O += P V  (split-bf16, 3 passes; Ps is wave-private)
    bf16x8 pah = *(const bf16x8*)&Ps[0][wave][cc][g * 8];
    bf16x8 pal = *(const bf16x8*)&Ps[1][wave][cc][g * 8];
#pragma unroll
    for (int n = 0; n < 6; ++n) {
      bf16x8 bvh = *(const bf16x8*)&Vt[0][n * 16 + cc][g * 8];
      bf16x8 bvl = *(const bf16x8*)&Vt[1][n * 16 + cc][g * 8];
      acc_o[n] = mfma16(pah, bvh, acc_o[n]);
      acc_o[n] = mfma16(pah, bvl, acc_o[n]);
      acc_o[n] = mfma16(pal, bvh, acc_o[n]);
    }
  }

  float snk = sink[head];
#pragma unroll
  for (int r = 0; r < 4; ++r) {
    float m2 = fmaxf(m_r[r], snk);
    float alpha = __expf(m_r[r] - m2);
    float denom = l_r[r] * alpha + __expf(snk - m2);
    float inv = 1.f / denom;
    int row = qs + wq0 + g * 4 + r;
#pragma unroll
    for (int n = 0; n < 6; ++n)
      out[(size_t)row * (NQ * VD) + head * VD + n * 16 + cc] = acc_o[n][r] * alpha * inv;
  }
}

// ---------------------------------------------------------------------------
// Router: one wave per token. top-2 of logits, 2-way softmax weights.
// ---------------------------------------------------------------------------
__global__ __launch_bounds__(64) void router_kernel(const float* __restrict__ x2,
    const float* __restrict__ gw, float* __restrict__ topkw, int* __restrict__ topkid)
{
  int t = blockIdx.x;
  int lane = threadIdx.x;
  float acc[NE];
#pragma unroll
  for (int e = 0; e < NE; ++e) acc[e] = 0.f;
  for (int hh = lane; hh < H; hh += 64) {
    float xv = x2[(size_t)t * H + hh];
    const float* g = gw + (size_t)hh * NE;
#pragma unroll
    for (int e = 0; e < NE; ++e) acc[e] = fmaf(xv, g[e], acc[e]);
  }
#pragma unroll
  for (int e = 0; e < NE; ++e)
#pragma unroll
    for (int off = 32; off > 0; off >>= 1) acc[e] += __shfl_xor(acc[e], off);
  if (lane == 0) {
    int b1 = 0; float v1 = acc[0];
#pragma unroll
    for (int e = 1; e < NE; ++e) { if (acc[e] > v1) { v1 = acc[e]; b1 = e; } }
    int b2 = -1; float v2 = -3.4e38f;
#pragma unroll
    for (int e = 0; e < NE; ++e) { if (e != b1 && acc[e] > v2) { v2 = acc[e]; b2 = e; } }
    float e2 = __expf(v2 - v1);
    float s = 1.f + e2;
    topkw[t * 2] = 1.f / s;
    topkw[t * 2 + 1] = e2 / s;
    topkid[t * 2] = b1;
    topkid[t * 2 + 1] = b2;
  }
}

// ---------------------------------------------------------------------------
// Build expert routing lists (single block).
// ---------------------------------------------------------------------------
__global__ __launch_bounds__(256) void route_build_kernel(
    const int* __restrict__ topkid, int* __restrict__ idssort,
    int* __restrict__ prow, int* __restrict__ eoffs)
{
  __shared__ int cnt[NE];
  __shared__ int off[NE + 1];
  __shared__ int cur[NE];
  int tid = threadIdx.x;
  if (tid < NE) cnt[tid] = 0;
  __syncthreads();
  for (int p = tid; p < T * TOPK; p += 256) atomicAdd(&cnt[topkid[p]], 1);
  __syncthreads();
  if (tid == 0) {
    off[0] = 0;
    for (int e = 0; e < NE; ++e) off[e + 1] = off[e] + cnt[e];
  }
  __syncthreads();
  if (tid < NE) cur[tid] = off[tid];
  __syncthreads();
  for (int p = tid; p < T * TOPK; p += 256) {
    int e = topkid[p];
    int ppos = atomicAdd(&cur[e], 1);
    idssort[ppos] = p >> 1;  // token
    prow[p] = ppos;
  }
  if (tid <= NE) eoffs[tid] = off[tid];
}

// ---------------------------------------------------------------------------
// act = silu(h1) * h2  (in place into h1)
// ---------------------------------------------------------------------------
__global__ __launch_bounds__(256) void silu_mul_kernel(float* __restrict__ h1,
    const float* __restrict__ h2, int n4)
{
  int i = blockIdx.x * 256 + threadIdx.x;
  if (i < n4) {
    float4 a = ((const float4*)h1)[i];
    float4 b = ((const float4*)h2)[i];
    float4 o;
    o.x = a.x / (1.f + __expf(-a.x)) * b.x;
    o.y = a.y / (1.f + __expf(-a.y)) * b.y;
    o.z = a.z / (1.f + __expf(-a.z)) * b.z;
    o.w = a.w / (1.f + __expf(-a.w)) * b.w;
    ((float4*)h1)[i] = o;
  }
}

// ---------------------------------------------------------------------------
// out[t] = h[t] + w0*eo[row0] + w1*eo[row1]
// ---------------------------------------------------------------------------
__global__ __launch_bounds__(256) void combine_kernel(const float* __restrict__ h,
    const float* __restrict__ eo, const float* __restrict__ topkw,
    const int* __restrict__ prow, float* __restrict__ out)
{
  int t = blockIdx.x, tid = threadIdx.x;
  float w0 = topkw[t * 2], w1 = topkw[t * 2 + 1];
  const float4* e0 = (const float4*)(eo + (size_t)prow[t * 2] * H);
  const float4* e1 = (const float4*)(eo + (size_t)prow[t * 2 + 1] * H);
  const float4* hp = (const float4*)(h + (size_t)t * H);
  float4* op = (float4*)(out + (size_t)t * H);
#pragma unroll
  for (int i = 0; i < 4; ++i) {
    int idx = tid + i * 256;
    float4 a = hp[idx], b = e0[idx], c = e1[idx];
    float4 o;
    o.x = a.x + w0 * b.x + w1 * c.x;
    o.y = a.y + w0 * b.y + w1 * c.y;
    o.z = a.z + w0 * b.z + w1 * c.z;
    o.w = a.w + w0 * b.w + w1 * c.w;
    op[idx] = o;
  }
}

// ---------------------------------------------------------------------------
extern "C" void kernel_launch(void* const* d_in, const int* in_sizes, int n_in,
                              void* d_out, int out_size, void* d_ws, size_t ws_size,
                              hipStream_t stream) {
  const int*   pos   = (const int*)d_in[0];
  const float* hid   = (const float*)d_in[1];
  const float* rms1w = (const float*)d_in[2];
  const float* rms2w = (const float*)d_in[3];
  const float* wq    = (const float*)d_in[4];
  const float* wk    = (const float*)d_in[5];
  const float* wv    = (const float*)d_in[6];
  const float* wo    = (const float*)d_in[7];
  const float* sink  = (const float*)d_in[8];
  const float* gw    = (const float*)d_in[9];
  const float* wgate = (const float*)d_in[10];
  const float* wup   = (const float*)d_in[11];
  const float* wdown = (const float*)d_in[12];
  float* out = (float*)d_out;

  char* ws = (char*)d_ws;
  float* x1 = (float*)(ws + 0);            // 33554432  (T*H)
  float* q  = (float*)(ws + 33554432);     // 33554432  (T*NQ*HD)
  float* kb = (float*)(ws + 67108864);     //  8388608  (T*NKV*HD)
  float* vb = (float*)(ws + 75497472);     //  6291456  (T*NKV*VD)
  float* ao = (float*)(ws + 81788928);     // 25165824  (T*NQ*VD)  -> h1 later
  float* h  = (float*)(ws + 106954752);    // 33554432
  float* x2 = (float*)(ws + 140509184);    // 33554432
  float* h2 = (float*)(ws + 174063616);    // 23068672  (T*K*FF)
  float* eo = (float*)(ws + 0);            // 67108864  (T*K*H) overlays x1,q
  float* h1 = ao;                          // (T*K*FF) fits in 25165824
  char* sm = ws + 197132288;
  float* topkw  = (float*)(sm);            // 16384
  int*  topkid  = (int*)(sm + 16384);      // 16384
  int*  prow    = (int*)(sm + 32768);      // 16384
  int*  idssort = (int*)(sm + 49152);      // 16384
  int*  eoffs   = (int*)(sm + 65536);      // 36

  // 1. x1 = rmsnorm(hid)
  rmsnorm_kernel<<<T, 256, 0, stream>>>(hid, rms1w, x1);
  // 2. q/k/v projections (split-bf16, ~f32 accurate)
  gemm_bf16<0, 1><<<dim3(32, 16, 1), 256, 0, stream>>>(x1, H, wq, NQ * HD, 0, q, NQ * HD,
      nullptr, nullptr, nullptr, T, NQ * HD, H);
  gemm_bf16<0, 1><<<dim3(8, 16, 1), 256, 0, stream>>>(x1, H, wk, NKV * HD, 0, kb, NKV * HD,
      nullptr, nullptr, nullptr, T, NKV * HD, H);
  gemm_bf16<0, 1><<<dim3(6, 16, 1), 256, 0, stream>>>(x1, H, wv, NKV * VD, 0, vb, NKV * VD,
      nullptr, nullptr, nullptr, T, NKV * VD, H);
  // 3. RoPE (in place)
  rope_kernel<<<T, 256, 0, stream>>>(pos, q, kb);
  // 4. attention (split-bf16)
  attn_kernel<<<dim3(T / 64, NQ, 1), 256, 0, stream>>>(q, kb, vb, sink, pos, ao);
  // 5. h = hid + ao @ wo (split-bf16)
  gemm_bf16<1, 1><<<dim3(32, 16, 1), 256, 0, stream>>>(ao, NQ * VD, wo, H, 0, h, H,
      hid, nullptr, nullptr, T, H, NQ * VD);
  // 6. x2 = rmsnorm(h)
  rmsnorm_kernel<<<T, 256, 0, stream>>>(h, rms2w, x2);
  // 7. routing (f32)
  router_kernel<<<T, 64, 0, stream>>>(x2, gw, topkw, topkid);
  route_build_kernel<<<1, 256, 0, stream>>>(topkid, idssort, prow, eoffs);
  // 8. MoE gate/up (gathered rows), silu*mul, down — plain bf16 (post-router)
  gemm_bf16<0, 0><<<dim3(11, 32, 8), 256, 0, stream>>>(x2, H, wgate, FF, (long long)H * FF,
      h1, FF, nullptr, idssort, eoffs, 0, FF, H);
  gemm_bf16<0, 0><<<dim3(11, 32, 8), 256, 0, stream>>>(x2, H, wup, FF, (long long)H * FF,
      h2, FF, nullptr, idssort, eoffs, 0, FF, H);
  silu_mul_kernel<<<(T * TOPK * FF / 4 + 255) / 256, 256, 0, stream>>>(h1, h2, T * TOPK * FF / 4);
  gemm_bf16<0, 0><<<dim3(32, 32, 8), 256, 0, stream>>>(h1, FF, wdown, H, (long long)FF * H,
      eo, H, nullptr, nullptr, eoffs, 0, H, FF);
  // 9. out = h + combine(eo)
  combine_kernel<<<T, 256, 0, stream>>>(h, eo, topkw, prow, out);
}

// Round 3
// 1638.095 us; speedup vs baseline: 1.6605x; 1.6605x over previous
//
#include <hip/hip_runtime.h>
#include <math.h>

#define T 2048
#define H 4096
#define NQ 32
#define NKV 8
#define HD 128
#define VD 96
#define WIN 1024
#define NE 8
#define FF 1408
#define TOPK 2

typedef __bf16 bf16x8 __attribute__((ext_vector_type(8)));
typedef unsigned short u16x8 __attribute__((ext_vector_type(8)));
typedef float f32x4 __attribute__((ext_vector_type(4)));

__device__ __forceinline__ unsigned short f2bf(float f) {
  union { float f; unsigned u; } v; v.f = f;
  unsigned r = v.u + 0x7fffu + ((v.u >> 16) & 1u);
  return (unsigned short)(r >> 16);
}
__device__ __forceinline__ float bf2f(unsigned short h) {
  union { unsigned u; float f; } v; v.u = ((unsigned)h) << 16;
  return v.f;
}
__device__ __forceinline__ f32x4 mfma16(bf16x8 a, bf16x8 b, f32x4 c) {
  return __builtin_amdgcn_mfma_f32_16x16x32_bf16(a, b, c, 0, 0, 0);
}
__device__ __forceinline__ f32x4 fzero4() { f32x4 z = {0.f, 0.f, 0.f, 0.f}; return z; }

struct Sel3 {
  const float* B[3];
  void* C[3];
  int nbend[3];
  int ldbn[3];
};

// ---------------------------------------------------------------------------
// GEMM with pre-split bf16 A (Ah [+Al]), f32 B converted during staging.
// C = A @ B.  SPLIT: 3-pass compensated (Ah·Bh + Ah·Bl + Al·Bh).
// GATHER: A row = row_idx[rowbase+grow].  EOFF: expert mode via blockIdx.z.
// OUTBF: store bf16(hi) into ushort C.  RES: C = acc + res.
// ---------------------------------------------------------------------------
template<int SPLIT, int GATHER, int EOFF, int OUTBF, int RES>
__global__ __launch_bounds__(256) void gemm_a16(
    const unsigned short* __restrict__ Ah, const unsigned short* __restrict__ Al,
    int lda, Sel3 sel, long long strideB,
    const float* __restrict__ res,
    const int* __restrict__ row_idx, const int* __restrict__ e_off,
    int M, int K)
{
  __shared__ __align__(16) unsigned short As[SPLIT ? 2 : 1][128][40];
  __shared__ __align__(16) unsigned short Bs[SPLIT ? 2 : 1][128][40];

  int rowbase = 0, Mloc = M;
  if (EOFF) {
    int e = blockIdx.z;
    rowbase = e_off[e];
    Mloc = e_off[e + 1] - rowbase;
  }
  int mtile = blockIdx.y * 128;
  if (mtile >= Mloc) return;

  int nb = blockIdx.x;
  int s = (nb < sel.nbend[0]) ? 0 : ((nb < sel.nbend[1]) ? 1 : 2);
  int nbase = (s == 0) ? 0 : sel.nbend[s - 1];
  int ldb = sel.ldbn[s];
  const float* B = sel.B[s];
  if (EOFF) B += strideB * (long long)blockIdx.z;
  int n0 = (nb - nbase) * 128;

  int tid = threadIdx.x;
  int lane = tid & 63, wave = tid >> 6;
  int g = lane >> 4, cc = lane & 15;
  int wrow = (wave >> 1) * 64, wcol = (wave & 1) * 64;

  f32x4 acc[4][4];
#pragma unroll
  for (int m = 0; m < 4; ++m)
#pragma unroll
    for (int n = 0; n < 4; ++n) acc[m][n] = fzero4();

  const u16x8 z8 = {0, 0, 0, 0, 0, 0, 0, 0};
  int nK = K >> 5;
  for (int kt = 0; kt < nK; ++kt) {
    int k0 = kt << 5;
    __syncthreads();
    // ---- stage A: 128 rows x 32 k, bf16 direct
#pragma unroll
    for (int i = 0; i < 2; ++i) {
      int c = tid + i * 256;
      int row = c >> 2, ks = (c & 3) << 3;
      int grow = mtile + row;
      u16x8 vh = z8, vl = z8;
      if (grow < Mloc) {
        long long ar = rowbase + grow;
        if (GATHER) ar = row_idx[ar];
        vh = *(const u16x8*)(Ah + (size_t)ar * lda + k0 + ks);
        if (SPLIT) vl = *(const u16x8*)(Al + (size_t)ar * lda + k0 + ks);
      }
      *(u16x8*)&As[0][row][ks] = vh;
      if (SPLIT) *(u16x8*)&As[1][row][ks] = vl;
    }
    // ---- stage B: read 4 k-rows x 4 n (float4), transpose, cvt, ds_write_b64
    {
      int nn = (tid & 31) << 2;
      int kb4 = (tid >> 5) << 2;
      const float* bp = B + (size_t)(k0 + kb4) * ldb + n0 + nn;
      float4 r0 = *(const float4*)bp;
      float4 r1 = *(const float4*)(bp + (size_t)ldb);
      float4 r2 = *(const float4*)(bp + 2 * (size_t)ldb);
      float4 r3 = *(const float4*)(bp + 3 * (size_t)ldb);
      ushort4 w;
      w.x = f2bf(r0.x); w.y = f2bf(r1.x); w.z = f2bf(r2.x); w.w = f2bf(r3.x);
      *(ushort4*)&Bs[0][nn + 0][kb4] = w;
      if (SPLIT) {
        ushort4 l; l.x = f2bf(r0.x - bf2f(w.x)); l.y = f2bf(r1.x - bf2f(w.y));
        l.z = f2bf(r2.x - bf2f(w.z)); l.w = f2bf(r3.x - bf2f(w.w));
        *(ushort4*)&Bs[1][nn + 0][kb4] = l;
      }
      w.x = f2bf(r0.y); w.y = f2bf(r1.y); w.z = f2bf(r2.y); w.w = f2bf(r3.y);
      *(ushort4*)&Bs[0][nn + 1][kb4] = w;
      if (SPLIT) {
        ushort4 l; l.x = f2bf(r0.y - bf2f(w.x)); l.y = f2bf(r1.y - bf2f(w.y));
        l.z = f2bf(r2.y - bf2f(w.z)); l.w = f2bf(r3.y - bf2f(w.w));
        *(ushort4*)&Bs[1][nn + 1][kb4] = l;
      }
      w.x = f2bf(r0.z); w.y = f2bf(r1.z); w.z = f2bf(r2.z); w.w = f2bf(r3.z);
      *(ushort4*)&Bs[0][nn + 2][kb4] = w;
      if (SPLIT) {
        ushort4 l; l.x = f2bf(r0.z - bf2f(w.x)); l.y = f2bf(r1.z - bf2f(w.y));
        l.z = f2bf(r2.z - bf2f(w.z)); l.w = f2bf(r3.z - bf2f(w.w));
        *(ushort4*)&Bs[1][nn + 2][kb4] = l;
      }
      w.x = f2bf(r0.w); w.y = f2bf(r1.w); w.z = f2bf(r2.w); w.w = f2bf(r3.w);
      *(ushort4*)&Bs[0][nn + 3][kb4] = w;
      if (SPLIT) {
        ushort4 l; l.x = f2bf(r0.w - bf2f(w.x)); l.y = f2bf(r1.w - bf2f(w.y));
        l.z = f2bf(r2.w - bf2f(w.z)); l.w = f2bf(r3.w - bf2f(w.w));
        *(ushort4*)&Bs[1][nn + 3][kb4] = l;
      }
    }
    __syncthreads();
    bf16x8 avh[4], bvh[4], avl[4], bvl[4];
#pragma unroll
    for (int m = 0; m < 4; ++m) {
      avh[m] = *(const bf16x8*)&As[0][wrow + m * 16 + cc][g * 8];
      if (SPLIT) avl[m] = *(const bf16x8*)&As[1][wrow + m * 16 + cc][g * 8];
    }
#pragma unroll
    for (int n = 0; n < 4; ++n) {
      bvh[n] = *(const bf16x8*)&Bs[0][wcol + n * 16 + cc][g * 8];
      if (SPLIT) bvl[n] = *(const bf16x8*)&Bs[1][wcol + n * 16 + cc][g * 8];
    }
#pragma unroll
    for (int m = 0; m < 4; ++m)
#pragma unroll
      for (int n = 0; n < 4; ++n) {
        acc[m][n] = mfma16(avh[m], bvh[n], acc[m][n]);
        if (SPLIT) {
          acc[m][n] = mfma16(avh[m], bvl[n], acc[m][n]);
          acc[m][n] = mfma16(avl[m], bvh[n], acc[m][n]);
        }
      }
  }

  int ldc = ldb;
#pragma unroll
  for (int m = 0; m < 4; ++m) {
    int rl = wrow + m * 16 + g * 4;
#pragma unroll
    for (int n = 0; n < 4; ++n) {
      int col = n0 + wcol + n * 16 + cc;
#pragma unroll
      for (int r = 0; r < 4; ++r) {
        int grow = mtile + rl + r;
        if (grow < Mloc) {
          size_t off = (size_t)(rowbase + grow) * ldc + col;
          float vv = acc[m][n][r];
          if (OUTBF) {
            ((unsigned short*)sel.C[s])[off] = f2bf(vv);
          } else {
            if (RES) vv += res[off];
            ((float*)sel.C[s])[off] = vv;
          }
        }
      }
    }
  }
}

// ---------------------------------------------------------------------------
// RMSNorm 1: f32 in -> bf16 hi/lo out.
// ---------------------------------------------------------------------------
__global__ __launch_bounds__(256) void rmsnorm_hl_kernel(const float* __restrict__ in,
    const float* __restrict__ w, unsigned short* __restrict__ oh,
    unsigned short* __restrict__ ol)
{
  int t = blockIdx.x;
  int tid = threadIdx.x;
  const float4* rp = (const float4*)(in + (size_t)t * H);
  const float4* wp = (const float4*)w;
  float4 vv[4];
  float ss = 0.f;
#pragma unroll
  for (int i = 0; i < 4; ++i) {
    vv[i] = rp[tid + i * 256];
    ss += vv[i].x * vv[i].x + vv[i].y * vv[i].y + vv[i].z * vv[i].z + vv[i].w * vv[i].w;
  }
#pragma unroll
  for (int off = 32; off > 0; off >>= 1) ss += __shfl_xor(ss, off);
  __shared__ float red[4];
  if ((tid & 63) == 0) red[tid >> 6] = ss;
  __syncthreads();
  float tot = red[0] + red[1] + red[2] + red[3];
  float rs = rsqrtf(tot * (1.f / H) + 1e-6f);
#pragma unroll
  for (int i = 0; i < 4; ++i) {
    float4 x = vv[i];
    float4 ww = wp[tid + i * 256];
    float y0 = x.x * rs * ww.x, y1 = x.y * rs * ww.y;
    float y2 = x.z * rs * ww.z, y3 = x.w * rs * ww.w;
    ushort4 hh, ll;
    hh.x = f2bf(y0); hh.y = f2bf(y1); hh.z = f2bf(y2); hh.w = f2bf(y3);
    ll.x = f2bf(y0 - bf2f(hh.x)); ll.y = f2bf(y1 - bf2f(hh.y));
    ll.z = f2bf(y2 - bf2f(hh.z)); ll.w = f2bf(y3 - bf2f(hh.w));
    *(ushort4*)&oh[(size_t)t * H + (tid + i * 256) * 4] = hh;
    *(ushort4*)&ol[(size_t)t * H + (tid + i * 256) * 4] = ll;
  }
}

// ---------------------------------------------------------------------------
// RMSNorm 2: f32 in -> f32 out (router) + bf16 hi out (MoE A operand).
// ---------------------------------------------------------------------------
__global__ __launch_bounds__(256) void rmsnorm_fh_kernel(const float* __restrict__ in,
    const float* __restrict__ w, float* __restrict__ of,
    unsigned short* __restrict__ oh)
{
  int t = blockIdx.x;
  int tid = threadIdx.x;
  const float4* rp = (const float4*)(in + (size_t)t * H);
  const float4* wp = (const float4*)w;
  float4 vv[4];
  float ss = 0.f;
#pragma unroll
  for (int i = 0; i < 4; ++i) {
    vv[i] = rp[tid + i * 256];
    ss += vv[i].x * vv[i].x + vv[i].y * vv[i].y + vv[i].z * vv[i].z + vv[i].w * vv[i].w;
  }
#pragma unroll
  for (int off = 32; off > 0; off >>= 1) ss += __shfl_xor(ss, off);
  __shared__ float red[4];
  if ((tid & 63) == 0) red[tid >> 6] = ss;
  __syncthreads();
  float tot = red[0] + red[1] + red[2] + red[3];
  float rs = rsqrtf(tot * (1.f / H) + 1e-6f);
#pragma unroll
  for (int i = 0; i < 4; ++i) {
    float4 x = vv[i];
    float4 ww = wp[tid + i * 256];
    float4 o;
    o.x = x.x * rs * ww.x; o.y = x.y * rs * ww.y;
    o.z = x.z * rs * ww.z; o.w = x.w * rs * ww.w;
    *(float4*)&of[(size_t)t * H + (tid + i * 256) * 4] = o;
    ushort4 hh;
    hh.x = f2bf(o.x); hh.y = f2bf(o.y); hh.z = f2bf(o.z); hh.w = f2bf(o.w);
    *(ushort4*)&oh[(size_t)t * H + (tid + i * 256) * 4] = hh;
  }
}

// ---------------------------------------------------------------------------
// RoPE + pack: read f32 q/k/v GEMM outputs, apply RoPE to q,k, emit bf16 hi/lo.
// ---------------------------------------------------------------------------
__global__ __launch_bounds__(256) void rope_pack_kernel(const int* __restrict__ pos,
    const float* __restrict__ qf, const float* __restrict__ kf, const float* __restrict__ vf,
    unsigned short* __restrict__ qh, unsigned short* __restrict__ ql,
    unsigned short* __restrict__ kh, unsigned short* __restrict__ kl,
    unsigned short* __restrict__ vh, unsigned short* __restrict__ vl)
{
  int t = blockIdx.x;
  float p = (float)pos[t];
  int tid = threadIdx.x;
  // q + k rope pairs
  for (int idx = tid; idx < (NQ + NKV) * 64; idx += 256) {
    const float* src; unsigned short *dh, *dl; size_t base; int d;
    if (idx < NQ * 64) {
      int hh = idx >> 6; d = idx & 63;
      base = (size_t)t * (NQ * HD) + hh * HD;
      src = qf; dh = qh; dl = ql;
    } else {
      int j = idx - NQ * 64;
      int hh = j >> 6; d = j & 63;
      base = (size_t)t * (NKV * HD) + hh * HD;
      src = kf; dh = kh; dl = kl;
    }
    float inv = exp2f(-19.931568569324174f * (float)(2 * d) * (1.0f / 128.0f));
    float ang = p * inv;
    float sn = sinf(ang), cs = cosf(ang);
    float x1 = src[base + d], x2 = src[base + d + 64];
    float o1 = x1 * cs - x2 * sn;
    float o2 = x2 * cs + x1 * sn;
    unsigned short h1 = f2bf(o1), h2 = f2bf(o2);
    dh[base + d] = h1; dl[base + d] = f2bf(o1 - bf2f(h1));
    dh[base + d + 64] = h2; dl[base + d + 64] = f2bf(o2 - bf2f(h2));
  }
  // v pack
  for (int idx = tid; idx < NKV * VD; idx += 256) {
    size_t o = (size_t)t * (NKV * VD) + idx;
    float v = vf[o];
    unsigned short hh = f2bf(v);
    vh[o] = hh; vl[o] = f2bf(v - bf2f(hh));
  }
}

// ---------------------------------------------------------------------------
// Flash attention, sliding window + sink; bf16 hi/lo inputs; split-bf16 MFMA.
// Output written as bf16 hi/lo (WO GEMM A operand).
// ---------------------------------------------------------------------------
__global__ __launch_bounds__(256) void attn_kernel(
    const unsigned short* __restrict__ qh, const unsigned short* __restrict__ ql,
    const unsigned short* __restrict__ kh, const unsigned short* __restrict__ kl,
    const unsigned short* __restrict__ vhp, const unsigned short* __restrict__ vlp,
    const float* __restrict__ sink, const int* __restrict__ pos,
    unsigned short* __restrict__ aoh, unsigned short* __restrict__ aol)
{
  __shared__ __align__(16) unsigned short Qs[2][64][136];
  __shared__ __align__(16) unsigned short Ks[2][32][136];
  __shared__ __align__(16) unsigned short Vt[2][96][40];
  __shared__ __align__(16) unsigned short Ps[2][4][16][40];
  __shared__ int posq[64];
  __shared__ int posk[32];

  const float SCALE = 0.08838834764831843f;
  int qs = blockIdx.x * 64;
  int head = blockIdx.y;
  int kvh = head >> 2;
  int tid = threadIdx.x;
  int lane = tid & 63, wave = tid >> 6;
  int g = lane >> 4, cc = lane & 15;
  int wq0 = wave * 16;

  // stage Q (64 x 128, hi+lo)
#pragma unroll
  for (int i = 0; i < 4; ++i) {
    int c = tid + i * 256;
    int row = c >> 4, ks = (c & 15) << 3;
    size_t gofs = (size_t)(qs + row) * (NQ * HD) + head * HD + ks;
    *(u16x8*)&Qs[0][row][ks] = *(const u16x8*)(qh + gofs);
    *(u16x8*)&Qs[1][row][ks] = *(const u16x8*)(ql + gofs);
  }
  if (tid < 64) posq[tid] = pos[qs + tid];

  float m_r[4], l_r[4];
  f32x4 acc_o[6];
#pragma unroll
  for (int r = 0; r < 4; ++r) { m_r[r] = -__builtin_huge_valf(); l_r[r] = 0.f; }
#pragma unroll
  for (int n = 0; n < 6; ++n) acc_o[n] = fzero4();

  int kstart = qs - (WIN - 1);
  if (kstart < 0) kstart = 0;
  kstart &= ~31;
  int kend = qs + 63;

  for (int k0 = kstart; k0 <= kend; k0 += 32) {
    __syncthreads();
#pragma unroll
    for (int i = 0; i < 2; ++i) {
      int c = tid + i * 256;
      int row = c >> 4, ks = (c & 15) << 3;
      size_t gofs = (size_t)(k0 + row) * (NKV * HD) + kvh * HD + ks;
      *(u16x8*)&Ks[0][row][ks] = *(const u16x8*)(kh + gofs);
      *(u16x8*)&Ks[1][row][ks] = *(const u16x8*)(kl + gofs);
    }
#pragma unroll
    for (int i = 0; i < 3; ++i) {
      int qd = tid + i * 256;
      int key = qd / 24, vq = qd % 24;
      size_t gofs = (size_t)(k0 + key) * (NKV * VD) + kvh * VD + vq * 4;
      ushort4 a = *(const ushort4*)(vhp + gofs);
      ushort4 b = *(const ushort4*)(vlp + gofs);
      Vt[0][vq * 4 + 0][key] = a.x; Vt[0][vq * 4 + 1][key] = a.y;
      Vt[0][vq * 4 + 2][key] = a.z; Vt[0][vq * 4 + 3][key] = a.w;
      Vt[1][vq * 4 + 0][key] = b.x; Vt[1][vq * 4 + 1][key] = b.y;
      Vt[1][vq * 4 + 2][key] = b.z; Vt[1][vq * 4 + 3][key] = b.w;
    }
    if (tid < 32) posk[tid] = pos[k0 + tid];
    __syncthreads();

    bf16x8 aqh[4], aql[4];
#pragma unroll
    for (int kk = 0; kk < 4; ++kk) {
      aqh[kk] = *(const bf16x8*)&Qs[0][wq0 + cc][kk * 32 + g * 8];
      aql[kk] = *(const bf16x8*)&Qs[1][wq0 + cc][kk * 32 + g * 8];
    }
    f32x4 sacc[2];
    sacc[0] = fzero4(); sacc[1] = fzero4();
#pragma unroll
    for (int kb = 0; kb < 2; ++kb)
#pragma unroll
      for (int kk = 0; kk < 4; ++kk) {
        bf16x8 bh = *(const bf16x8*)&Ks[0][kb * 16 + cc][kk * 32 + g * 8];
        bf16x8 bl = *(const bf16x8*)&Ks[1][kb * 16 + cc][kk * 32 + g * 8];
        sacc[kb] = mfma16(aqh[kk], bh, sacc[kb]);
        sacc[kb] = mfma16(aqh[kk], bl, sacc[kb]);
        sacc[kb] = mfma16(aql[kk], bh, sacc[kb]);
      }

    int j0 = posk[cc], j1 = posk[16 + cc];
#pragma unroll
    for (int r = 0; r < 4; ++r) {
      int irow = posq[wq0 + g * 4 + r];
      float s0 = sacc[0][r] * SCALE;
      float s1 = sacc[1][r] * SCALE;
      bool ok0 = (j0 <= irow) && (irow - j0 < WIN);
      bool ok1 = (j1 <= irow) && (irow - j1 < WIN);
      if (!ok0) s0 = -1e30f;
      if (!ok1) s1 = -1e30f;
      float rm = fmaxf(s0, s1);
#pragma unroll
      for (int off = 1; off < 16; off <<= 1) rm = fmaxf(rm, __shfl_xor(rm, off));
      float mn = fmaxf(m_r[r], rm);
      float p0 = ok0 ? __expf(s0 - mn) : 0.f;
      float p1 = ok1 ? __expf(s1 - mn) : 0.f;
      float rs = p0 + p1;
#pragma unroll
      for (int off = 1; off < 16; off <<= 1) rs += __shfl_xor(rs, off);
      float alpha = __expf(m_r[r] - mn);
      l_r[r] = l_r[r] * alpha + rs;
      m_r[r] = mn;
#pragma unroll
      for (int n = 0; n < 6; ++n) acc_o[n][r] *= alpha;
      unsigned short p0h = f2bf(p0), p1h = f2bf(p1);
      Ps[0][wave][g * 4 + r][cc] = p0h;
      Ps[1][wave][g * 4 + r][cc] = f2bf(p0 - bf2f(p0h));
      Ps[0][wave][g * 4 + r][16 + cc] = p1h;
      Ps[1][wave][g * 4 + r][16 + cc] = f2bf(p1 - bf2f(p1h));
    }
    bf16x8 pah = *(const bf16x8*)&Ps[0][wave][cc][g * 8];
    bf16x8 pal = *(const bf16x8*)&Ps[1][wave][cc][g * 8];
#pragma unroll
    for (int n = 0; n < 6; ++n) {
      bf16x8 bh = *(const bf16x8*)&Vt[0][n * 16 + cc][g * 8];
      bf16x8 bl = *(const bf16x8*)&Vt[1][n * 16 + cc][g * 8];
      acc_o[n] = mfma16(pah, bh, acc_o[n]);
      acc_o[n] = mfma16(pah, bl, acc_o[n]);
      acc_o[n] = mfma16(pal, bh, acc_o[n]);
    }
  }

  float snk = sink[head];
#pragma unroll
  for (int r = 0; r < 4; ++r) {
    float m2 = fmaxf(m_r[r], snk);
    float alpha = __expf(m_r[r] - m2);
    float denom = l_r[r] * alpha + __expf(snk - m2);
    float inv = 1.f / denom;
    int row = qs + wq0 + g * 4 + r;
#pragma unroll
    for (int n = 0; n < 6; ++n) {
      float val = acc_o[n][r] * alpha * inv;
      size_t off = (size_t)row * (NQ * VD) + head * VD + n * 16 + cc;
      unsigned short hh = f2bf(val);
      aoh[off] = hh;
      aol[off] = f2bf(val - bf2f(hh));
    }
  }
}

// ---------------------------------------------------------------------------
// Router: one wave per token.
// ---------------------------------------------------------------------------
__global__ __launch_bounds__(64) void router_kernel(const float* __restrict__ x2,
    const float* __restrict__ gw, float* __restrict__ topkw, int* __restrict__ topkid)
{
  int t = blockIdx.x;
  int lane = threadIdx.x;
  float acc[NE];
#pragma unroll
  for (int e = 0; e < NE; ++e) acc[e] = 0.f;
  for (int hh = lane; hh < H; hh += 64) {
    float xv = x2[(size_t)t * H + hh];
    const float* g = gw + (size_t)hh * NE;
#pragma unroll
    for (int e = 0; e < NE; ++e) acc[e] = fmaf(xv, g[e], acc[e]);
  }
#pragma unroll
  for (int e = 0; e < NE; ++e)
#pragma unroll
    for (int off = 32; off > 0; off >>= 1) acc[e] += __shfl_xor(acc[e], off);
  if (lane == 0) {
    int b1 = 0; float v1 = acc[0];
#pragma unroll
    for (int e = 1; e < NE; ++e) { if (acc[e] > v1) { v1 = acc[e]; b1 = e; } }
    int b2 = -1; float v2 = -3.4e38f;
#pragma unroll
    for (int e = 0; e < NE; ++e) { if (e != b1 && acc[e] > v2) { v2 = acc[e]; b2 = e; } }
    float e2 = __expf(v2 - v1);
    float s = 1.f + e2;
    topkw[t * 2] = 1.f / s;
    topkw[t * 2 + 1] = e2 / s;
    topkid[t * 2] = b1;
    topkid[t * 2 + 1] = b2;
  }
}

__global__ __launch_bounds__(256) void route_build_kernel(
    const int* __restrict__ topkid, int* __restrict__ idssort,
    int* __restrict__ prow, int* __restrict__ eoffs)
{
  __shared__ int cnt[NE];
  __shared__ int off[NE + 1];
  __shared__ int cur[NE];
  int tid = threadIdx.x;
  if (tid < NE) cnt[tid] = 0;
  __syncthreads();
  for (int p = tid; p < T * TOPK; p += 256) atomicAdd(&cnt[topkid[p]], 1);
  __syncthreads();
  if (tid == 0) {
    off[0] = 0;
    for (int e = 0; e < NE; ++e) off[e + 1] = off[e] + cnt[e];
  }
  __syncthreads();
  if (tid < NE) cur[tid] = off[tid];
  __syncthreads();
  for (int p = tid; p < T * TOPK; p += 256) {
    int e = topkid[p];
    int ppos = atomicAdd(&cur[e], 1);
    idssort[ppos] = p >> 1;
    prow[p] = ppos;
  }
  if (tid <= NE) eoffs[tid] = off[tid];
}

// ---------------------------------------------------------------------------
// silu(h1)*h2 on bf16 inputs -> bf16 out (down-GEMM A operand).
// ---------------------------------------------------------------------------
__global__ __launch_bounds__(256) void silu_mul_kernel(
    const unsigned short* __restrict__ h1b, const unsigned short* __restrict__ h2b,
    unsigned short* __restrict__ oh, int n8)
{
  int i = blockIdx.x * 256 + threadIdx.x;
  if (i < n8) {
    ushort4 a0 = ((const ushort4*)h1b)[i * 2], a1 = ((const ushort4*)h1b)[i * 2 + 1];
    ushort4 b0 = ((const ushort4*)h2b)[i * 2], b1 = ((const ushort4*)h2b)[i * 2 + 1];
    ushort4 o0, o1;
    float x, y, r;
    x = bf2f(a0.x); y = bf2f(b0.x); r = x / (1.f + __expf(-x)) * y; o0.x = f2bf(r);
    x = bf2f(a0.y); y = bf2f(b0.y); r = x / (1.f + __expf(-x)) * y; o0.y = f2bf(r);
    x = bf2f(a0.z); y = bf2f(b0.z); r = x / (1.f + __expf(-x)) * y; o0.z = f2bf(r);
    x = bf2f(a0.w); y = bf2f(b0.w); r = x / (1.f + __expf(-x)) * y; o0.w = f2bf(r);
    x = bf2f(a1.x); y = bf2f(b1.x); r = x / (1.f + __expf(-x)) * y; o1.x = f2bf(r);
    x = bf2f(a1.y); y = bf2f(b1.y); r = x / (1.f + __expf(-x)) * y; o1.y = f2bf(r);
    x = bf2f(a1.z); y = bf2f(b1.z); r = x / (1.f + __expf(-x)) * y; o1.z = f2bf(r);
    x = bf2f(a1.w); y = bf2f(b1.w); r = x / (1.f + __expf(-x)) * y; o1.w = f2bf(r);
    ((ushort4*)oh)[i * 2] = o0;
    ((ushort4*)oh)[i * 2 + 1] = o1;
  }
}

__global__ __launch_bounds__(256) void combine_kernel(const float* __restrict__ h,
    const float* __restrict__ eo, const float* __restrict__ topkw,
    const int* __restrict__ prow, float* __restrict__ out)
{
  int t = blockIdx.x, tid = threadIdx.x;
  float w0 = topkw[t * 2], w1 = topkw[t * 2 + 1];
  const float4* e0 = (const float4*)(eo + (size_t)prow[t * 2] * H);
  const float4* e1 = (const float4*)(eo + (size_t)prow[t * 2 + 1] * H);
  const float4* hp = (const float4*)(h + (size_t)t * H);
  float4* op = (float4*)(out + (size_t)t * H);
#pragma unroll
  for (int i = 0; i < 4; ++i) {
    int idx = tid + i * 256;
    float4 a = hp[idx], b = e0[idx], c = e1[idx];
    float4 o;
    o.x = a.x + w0 * b.x + w1 * c.x;
    o.y = a.y + w0 * b.y + w1 * c.y;
    o.z = a.z + w0 * b.z + w1 * c.z;
    o.w = a.w + w0 * b.w + w1 * c.w;
    op[idx] = o;
  }
}

// ---------------------------------------------------------------------------
extern "C" void kernel_launch(void* const* d_in, const int* in_sizes, int n_in,
                              void* d_out, int out_size, void* d_ws, size_t ws_size,
                              hipStream_t stream) {
  const int*   pos   = (const int*)d_in[0];
  const float* hid   = (const float*)d_in[1];
  const float* rms1w = (const float*)d_in[2];
  const float* rms2w = (const float*)d_in[3];
  const float* wq    = (const float*)d_in[4];
  const float* wk    = (const float*)d_in[5];
  const float* wv    = (const float*)d_in[6];
  const float* wo    = (const float*)d_in[7];
  const float* sink  = (const float*)d_in[8];
  const float* gw    = (const float*)d_in[9];
  const float* wgate = (const float*)d_in[10];
  const float* wup   = (const float*)d_in[11];
  const float* wdown = (const float*)d_in[12];
  float* out = (float*)d_out;

  char* ws = (char*)d_ws;
  const size_t MB = 1048576ull;
  unsigned short* x1h = (unsigned short*)(ws + 0 * MB);
  unsigned short* x1l = (unsigned short*)(ws + 16 * MB);
  float* qf  = (float*)(ws + 32 * MB);
  float* kbf = (float*)(ws + 64 * MB);
  float* vbf = (float*)(ws + 72 * MB);
  unsigned short* qh = (unsigned short*)(ws + 0 * MB);    // over x1h (dead)
  unsigned short* ql = (unsigned short*)(ws + 16 * MB);   // over x1l (dead)
  unsigned short* kh = (unsigned short*)(ws + 80 * MB);
  unsigned short* kl = (unsigned short*)(ws + 84 * MB);
  unsigned short* vh = (unsigned short*)(ws + 88 * MB);
  unsigned short* vl = (unsigned short*)(ws + 91 * MB);
  unsigned short* aoh = (unsigned short*)(ws + 94 * MB);
  unsigned short* aol = (unsigned short*)(ws + 106 * MB);
  float* h   = (float*)(ws + 118 * MB);
  float* x2  = (float*)(ws + 32 * MB);                    // over qf (dead)
  unsigned short* x2h = (unsigned short*)(ws + 64 * MB);  // over kbf/vbf (dead)
  unsigned short* h1b = (unsigned short*)(ws + 150 * MB);
  unsigned short* h2b = (unsigned short*)(ws + 162 * MB);
  unsigned short* h1h = (unsigned short*)(ws + 80 * MB);  // over kh..vl (dead)
  float* eo  = (float*)(ws + 0 * MB);                     // over qh/ql/x2 (dead)
  char* sm = ws + 174 * MB;
  float* topkw  = (float*)(sm);
  int*  topkid  = (int*)(sm + 16384);
  int*  prow    = (int*)(sm + 32768);
  int*  idssort = (int*)(sm + 49152);
  int*  eoffs   = (int*)(sm + 65536);

  // 1. x1 = rmsnorm(hid) -> bf16 hi/lo
  rmsnorm_hl_kernel<<<T, 256, 0, stream>>>(hid, rms1w, x1h, x1l);

  // 2. fused QKV GEMM (split): N-blocks [0,32)=q, [32,40)=k, [40,46)=v
  {
    Sel3 sel;
    sel.B[0] = wq;  sel.B[1] = wk;  sel.B[2] = wv;
    sel.C[0] = qf;  sel.C[1] = kbf; sel.C[2] = vbf;
    sel.nbend[0] = 32; sel.nbend[1] = 40; sel.nbend[2] = 46;
    sel.ldbn[0] = NQ * HD; sel.ldbn[1] = NKV * HD; sel.ldbn[2] = NKV * VD;
    gemm_a16<1, 0, 0, 0, 0><<<dim3(46, 16, 1), 256, 0, stream>>>(
        x1h, x1l, H, sel, 0, nullptr, nullptr, nullptr, T, H);
  }

  // 3. RoPE + pack q/k/v to bf16 hi/lo
  rope_pack_kernel<<<T, 256, 0, stream>>>(pos, qf, kbf, vbf, qh, ql, kh, kl, vh, vl);

  // 4. attention -> aoh/aol
  attn_kernel<<<dim3(T / 64, NQ, 1), 256, 0, stream>>>(qh, ql, kh, kl, vh, vl,
      sink, pos, aoh, aol);

  // 5. h = hid + ao @ wo (split)
  {
    Sel3 sel;
    sel.B[0] = wo; sel.B[1] = wo; sel.B[2] = wo;
    sel.C[0] = h;  sel.C[1] = h;  sel.C[2] = h;
    sel.nbend[0] = 32; sel.nbend[1] = 32; sel.nbend[2] = 32;
    sel.ldbn[0] = H; sel.ldbn[1] = H; sel.ldbn[2] = H;
    gemm_a16<1, 0, 0, 0, 1><<<dim3(32, 16, 1), 256, 0, stream>>>(
        aoh, aol, NQ * VD, sel, 0, hid, nullptr, nullptr, T, NQ * VD);
  }

  // 6. x2 = rmsnorm(h) -> f32 + bf16 hi
  rmsnorm_fh_kernel<<<T, 256, 0, stream>>>(h, rms2w, x2, x2h);

  // 7. routing
  router_kernel<<<T, 64, 0, stream>>>(x2, gw, topkw, topkid);
  route_build_kernel<<<1, 256, 0, stream>>>(topkid, idssort, prow, eoffs);

  // 8. MoE gate+up fused (1-pass, bf16 out), silu, down
  {
    Sel3 sel;
    sel.B[0] = wgate; sel.B[1] = wup; sel.B[2] = wup;
    sel.C[0] = h1b;   sel.C[1] = h2b; sel.C[2] = h2b;
    sel.nbend[0] = 11; sel.nbend[1] = 22; sel.nbend[2] = 22;
    sel.ldbn[0] = FF; sel.ldbn[1] = FF; sel.ldbn[2] = FF;
    gemm_a16<0, 1, 1, 1, 0><<<dim3(22, 32, 8), 256, 0, stream>>>(
        x2h, nullptr, H, sel, (long long)H * FF, nullptr, idssort, eoffs, 0, H);
  }
  silu_mul_kernel<<<(T * TOPK * FF / 8 + 255) / 256, 256, 0, stream>>>(
      h1b, h2b, h1h, T * TOPK * FF / 8);
  {
    Sel3 sel;
    sel.B[0] = wdown; sel.B[1] = wdown; sel.B[2] = wdown;
    sel.C[0] = eo;    sel.C[1] = eo;   sel.C[2] = eo;
    sel.nbend[0] = 32; sel.nbend[1] = 32; sel.nbend[2] = 32;
    sel.ldbn[0] = H; sel.ldbn[1] = H; sel.ldbn[2] = H;
    gemm_a16<0, 0, 1, 0, 0><<<dim3(32, 32, 8), 256, 0, stream>>>(
        h1h, nullptr, FF, sel, (long long)FF * H, nullptr, nullptr, eoffs, 0, FF);
  }

  // 9. out = h + combine(eo)
  combine_kernel<<<T, 256, 0, stream>>>(h, eo, topkw, prow, out);
}

// Round 4
// 1523.174 us; speedup vs baseline: 1.7858x; 1.0754x over previous
//
#include <hip/hip_runtime.h>
#include <math.h>

#define T 2048
#define H 4096
#define NQ 32
#define NKV 8
#define HD 128
#define VD 96
#define WIN 1024
#define NE 8
#define FF 1408
#define TOPK 2

typedef __bf16 bf16x8 __attribute__((ext_vector_type(8)));
typedef unsigned short u16x8 __attribute__((ext_vector_type(8)));
typedef float f32x4 __attribute__((ext_vector_type(4)));
typedef unsigned short ushort_t;

__device__ __forceinline__ unsigned short f2bf(float f) {
  union { float f; unsigned u; } v; v.f = f;
  unsigned r = v.u + 0x7fffu + ((v.u >> 16) & 1u);
  return (unsigned short)(r >> 16);
}
__device__ __forceinline__ float bf2f(unsigned short h) {
  union { unsigned u; float f; } v; v.u = ((unsigned)h) << 16;
  return v.f;
}
__device__ __forceinline__ f32x4 mfma16(bf16x8 a, bf16x8 b, f32x4 c) {
  return __builtin_amdgcn_mfma_f32_16x16x32_bf16(a, b, c, 0, 0, 0);
}
__device__ __forceinline__ f32x4 fzero4() { f32x4 z = {0.f, 0.f, 0.f, 0.f}; return z; }

// async global->LDS 16B copy. Dest must be linear: wave base + lane*16.
__device__ __forceinline__ void gl16(const void* g, void* l) {
  __builtin_amdgcn_global_load_lds(
      (const __attribute__((address_space(1))) void*)g,
      (__attribute__((address_space(3))) void*)l, 16, 0, 0);
}

// ---------------------------------------------------------------------------
// Transpose + f32->bf16 convert: src [R][C] f32 -> dst BT rows [dro+c][r].
// SPLITOUT=1 also writes the bf16 compensation term to dl.
// grid: (C/64, R/64, E)
// ---------------------------------------------------------------------------
template<int SPLITOUT>
__global__ __launch_bounds__(256) void tconv_kernel(
    const float* __restrict__ src, int ldsrc,
    ushort_t* __restrict__ dh, ushort_t* __restrict__ dl,
    int lddst, int dro, long long sE, long long dE)
{
  __shared__ float tile[64][65];
  int e = blockIdx.z;
  src += sE * (long long)e;
  dh += dE * (long long)e;
  if (SPLITOUT) dl += dE * (long long)e;
  int c0 = blockIdx.x * 64;
  int r0 = blockIdx.y * 64;
  int tid = threadIdx.x;
#pragma unroll
  for (int i = 0; i < 4; ++i) {
    int idx = tid + i * 256;          // 1024 float4 slots
    int r = idx >> 4, c4 = (idx & 15) << 2;
    float4 v = *(const float4*)&src[(size_t)(r0 + r) * ldsrc + c0 + c4];
    tile[r][c4 + 0] = v.x; tile[r][c4 + 1] = v.y;
    tile[r][c4 + 2] = v.z; tile[r][c4 + 3] = v.w;
  }
  __syncthreads();
#pragma unroll
  for (int i = 0; i < 2; ++i) {
    int idx = tid + i * 256;          // 512 slots: 64 cols x 8 row-groups
    int c = idx >> 3, r8 = (idx & 7) << 3;
    u16x8 hv, lv;
#pragma unroll
    for (int j = 0; j < 8; ++j) {
      float f = tile[r8 + j][c];
      unsigned short hh = f2bf(f);
      hv[j] = hh;
      if (SPLITOUT) lv[j] = f2bf(f - bf2f(hh));
    }
    size_t o = (size_t)(dro + c0 + c) * lddst + r0 + r8;
    *(u16x8*)&dh[o] = hv;
    if (SPLITOUT) *(u16x8*)&dl[o] = lv;
  }
}

// ---------------------------------------------------------------------------
// m97-style GEMM: A bf16 [M][K] (pre-split hi/lo), B bf16 BT [N][K].
// global_load_lds staging into linear [128][32] LDS tiles; 128x128 C tile.
// SPLIT: 3-pass compensated. GATHER: A row gather. EOFF: per-expert mode.
// OUTBF: bf16 C. RES: C = acc + res.
// ---------------------------------------------------------------------------
template<int SPLIT, int GATHER, int EOFF, int OUTBF, int RES>
__global__ __launch_bounds__(256) void gemm_bt(
    const ushort_t* __restrict__ Ah, const ushort_t* __restrict__ Al, int lda,
    const ushort_t* __restrict__ Bh, const ushort_t* __restrict__ Bl,
    long long strideBe,
    void* __restrict__ Cp, int ldc,
    const float* __restrict__ res,
    const int* __restrict__ row_idx, const int* __restrict__ e_off,
    int M, int K)
{
  __shared__ __align__(16) ushort_t As[(SPLIT ? 2 : 1) * 4096];
  __shared__ __align__(16) ushort_t Bs[(SPLIT ? 2 : 1) * 4096];

  int rowbase = 0, Mloc = M;
  if (EOFF) {
    int e = blockIdx.z;
    rowbase = e_off[e];
    Mloc = e_off[e + 1] - rowbase;
    Bh += strideBe * (long long)e;
    if (SPLIT) Bl += strideBe * (long long)e;
  }
  int mtile = blockIdx.y * 128;
  if (mtile >= Mloc) return;
  int n0 = blockIdx.x * 128;

  int tid = threadIdx.x;
  int lane = tid & 63, wave = tid >> 6;
  int g = lane >> 4, cc = lane & 15;
  int wrow = (wave >> 1) * 64, wcol = (wave & 1) * 64;

  // staging source pointers (2 x 16B per tile per thread)
  int ks = (tid & 3) << 3;            // k element offset 0/8/16/24
  const ushort_t *aph0, *aph1, *apl0 = nullptr, *apl1 = nullptr;
  {
    int r0 = (tid >> 2), r1 = (tid >> 2) + 64;
    long long ar0, ar1;
    if (EOFF || GATHER) {
      int g0 = mtile + r0; if (g0 >= Mloc) g0 = 0;
      int g1 = mtile + r1; if (g1 >= Mloc) g1 = 0;
      if (GATHER) { ar0 = row_idx[rowbase + g0]; ar1 = row_idx[rowbase + g1]; }
      else { ar0 = rowbase + g0; ar1 = rowbase + g1; }
    } else {
      ar0 = mtile + r0; ar1 = mtile + r1;
    }
    aph0 = Ah + ar0 * lda + ks;
    aph1 = Ah + ar1 * lda + ks;
    if (SPLIT) { apl0 = Al + ar0 * lda + ks; apl1 = Al + ar1 * lda + ks; }
  }
  const ushort_t* bph0 = Bh + (size_t)(n0 + (tid >> 2)) * K + ks;
  const ushort_t* bph1 = Bh + (size_t)(n0 + (tid >> 2) + 64) * K + ks;
  const ushort_t* bpl0 = SPLIT ? Bl + (size_t)(n0 + (tid >> 2)) * K + ks : nullptr;
  const ushort_t* bpl1 = SPLIT ? Bl + (size_t)(n0 + (tid >> 2) + 64) * K + ks : nullptr;
  ushort_t* la0 = As + tid * 8;
  ushort_t* la1 = As + (tid + 256) * 8;
  ushort_t* lb0 = Bs + tid * 8;
  ushort_t* lb1 = Bs + (tid + 256) * 8;

  f32x4 acc[4][4];
#pragma unroll
  for (int m = 0; m < 4; ++m)
#pragma unroll
    for (int n = 0; n < 4; ++n) acc[m][n] = fzero4();

  int nK = K >> 5;
  for (int kt = 0; kt < nK; ++kt) {
    int k0 = kt << 5;
    gl16(aph0 + k0, la0);
    gl16(aph1 + k0, la1);
    gl16(bph0 + k0, lb0);
    gl16(bph1 + k0, lb1);
    if (SPLIT) {
      gl16(apl0 + k0, la0 + 4096);
      gl16(apl1 + k0, la1 + 4096);
      gl16(bpl0 + k0, lb0 + 4096);
      gl16(bpl1 + k0, lb1 + 4096);
    }
    __syncthreads();
    bf16x8 avh[4], bvh[4], avl[4], bvl[4];
#pragma unroll
    for (int m = 0; m < 4; ++m) {
      int row = wrow + m * 16 + cc;
      avh[m] = *(const bf16x8*)&As[row * 32 + g * 8];
      if (SPLIT) avl[m] = *(const bf16x8*)&As[4096 + row * 32 + g * 8];
    }
#pragma unroll
    for (int n = 0; n < 4; ++n) {
      int row = wcol + n * 16 + cc;
      bvh[n] = *(const bf16x8*)&Bs[row * 32 + g * 8];
      if (SPLIT) bvl[n] = *(const bf16x8*)&Bs[4096 + row * 32 + g * 8];
    }
#pragma unroll
    for (int m = 0; m < 4; ++m)
#pragma unroll
      for (int n = 0; n < 4; ++n) {
        acc[m][n] = mfma16(avh[m], bvh[n], acc[m][n]);
        if (SPLIT) {
          acc[m][n] = mfma16(avh[m], bvl[n], acc[m][n]);
          acc[m][n] = mfma16(avl[m], bvh[n], acc[m][n]);
        }
      }
    __syncthreads();
  }

#pragma unroll
  for (int m = 0; m < 4; ++m) {
    int rl = wrow + m * 16 + g * 4;
#pragma unroll
    for (int n = 0; n < 4; ++n) {
      int col = n0 + wcol + n * 16 + cc;
#pragma unroll
      for (int r = 0; r < 4; ++r) {
        int grow = mtile + rl + r;
        if (grow < Mloc) {
          size_t off = (size_t)(rowbase + grow) * ldc + col;
          float vv = acc[m][n][r];
          if (OUTBF) {
            ((ushort_t*)Cp)[off] = f2bf(vv);
          } else {
            if (RES) vv += res[off];
            ((float*)Cp)[off] = vv;
          }
        }
      }
    }
  }
}

// ---------------------------------------------------------------------------
// RMSNorm 1: f32 in -> bf16 hi/lo out.
// ---------------------------------------------------------------------------
__global__ __launch_bounds__(256) void rmsnorm_hl_kernel(const float* __restrict__ in,
    const float* __restrict__ w, ushort_t* __restrict__ oh, ushort_t* __restrict__ ol)
{
  int t = blockIdx.x;
  int tid = threadIdx.x;
  const float4* rp = (const float4*)(in + (size_t)t * H);
  const float4* wp = (const float4*)w;
  float4 vv[4];
  float ss = 0.f;
#pragma unroll
  for (int i = 0; i < 4; ++i) {
    vv[i] = rp[tid + i * 256];
    ss += vv[i].x * vv[i].x + vv[i].y * vv[i].y + vv[i].z * vv[i].z + vv[i].w * vv[i].w;
  }
#pragma unroll
  for (int off = 32; off > 0; off >>= 1) ss += __shfl_xor(ss, off);
  __shared__ float red[4];
  if ((tid & 63) == 0) red[tid >> 6] = ss;
  __syncthreads();
  float tot = red[0] + red[1] + red[2] + red[3];
  float rs = rsqrtf(tot * (1.f / H) + 1e-6f);
#pragma unroll
  for (int i = 0; i < 4; ++i) {
    float4 x = vv[i];
    float4 ww = wp[tid + i * 256];
    float y0 = x.x * rs * ww.x, y1 = x.y * rs * ww.y;
    float y2 = x.z * rs * ww.z, y3 = x.w * rs * ww.w;
    ushort4 hh, ll;
    hh.x = f2bf(y0); hh.y = f2bf(y1); hh.z = f2bf(y2); hh.w = f2bf(y3);
    ll.x = f2bf(y0 - bf2f(hh.x)); ll.y = f2bf(y1 - bf2f(hh.y));
    ll.z = f2bf(y2 - bf2f(hh.z)); ll.w = f2bf(y3 - bf2f(hh.w));
    *(ushort4*)&oh[(size_t)t * H + (tid + i * 256) * 4] = hh;
    *(ushort4*)&ol[(size_t)t * H + (tid + i * 256) * 4] = ll;
  }
}

// ---------------------------------------------------------------------------
// RMSNorm 2: f32 in -> f32 out (router) + bf16 hi out (MoE A operand).
// ---------------------------------------------------------------------------
__global__ __launch_bounds__(256) void rmsnorm_fh_kernel(const float* __restrict__ in,
    const float* __restrict__ w, float* __restrict__ of, ushort_t* __restrict__ oh)
{
  int t = blockIdx.x;
  int tid = threadIdx.x;
  const float4* rp = (const float4*)(in + (size_t)t * H);
  const float4* wp = (const float4*)w;
  float4 vv[4];
  float ss = 0.f;
#pragma unroll
  for (int i = 0; i < 4; ++i) {
    vv[i] = rp[tid + i * 256];
    ss += vv[i].x * vv[i].x + vv[i].y * vv[i].y + vv[i].z * vv[i].z + vv[i].w * vv[i].w;
  }
#pragma unroll
  for (int off = 32; off > 0; off >>= 1) ss += __shfl_xor(ss, off);
  __shared__ float red[4];
  if ((tid & 63) == 0) red[tid >> 6] = ss;
  __syncthreads();
  float tot = red[0] + red[1] + red[2] + red[3];
  float rs = rsqrtf(tot * (1.f / H) + 1e-6f);
#pragma unroll
  for (int i = 0; i < 4; ++i) {
    float4 x = vv[i];
    float4 ww = wp[tid + i * 256];
    float4 o;
    o.x = x.x * rs * ww.x; o.y = x.y * rs * ww.y;
    o.z = x.z * rs * ww.z; o.w = x.w * rs * ww.w;
    *(float4*)&of[(size_t)t * H + (tid + i * 256) * 4] = o;
    ushort4 hh;
    hh.x = f2bf(o.x); hh.y = f2bf(o.y); hh.z = f2bf(o.z); hh.w = f2bf(o.w);
    *(ushort4*)&oh[(size_t)t * H + (tid + i * 256) * 4] = hh;
  }
}

// ---------------------------------------------------------------------------
// RoPE + pack from fused qkv f32 [T][5888] -> bf16 hi/lo q/k/v buffers.
// ---------------------------------------------------------------------------
__global__ __launch_bounds__(256) void rope_pack_kernel(const int* __restrict__ pos,
    const float* __restrict__ qkv,
    ushort_t* __restrict__ qh, ushort_t* __restrict__ ql,
    ushort_t* __restrict__ kh, ushort_t* __restrict__ kl,
    ushort_t* __restrict__ vh, ushort_t* __restrict__ vl)
{
  int t = blockIdx.x;
  float p = (float)pos[t];
  int tid = threadIdx.x;
  const float* row = qkv + (size_t)t * 5888;
  for (int idx = tid; idx < (NQ + NKV) * 64; idx += 256) {
    int col; ushort_t *dh, *dl; size_t dbase; int d;
    if (idx < NQ * 64) {
      int hh = idx >> 6; d = idx & 63;
      col = hh * HD + d;
      dbase = (size_t)t * (NQ * HD) + hh * HD;
      dh = qh; dl = ql;
    } else {
      int j = idx - NQ * 64;
      int hh = j >> 6; d = j & 63;
      col = 4096 + hh * HD + d;
      dbase = (size_t)t * (NKV * HD) + hh * HD;
      dh = kh; dl = kl;
    }
    float inv = exp2f(-19.931568569324174f * (float)(2 * d) * (1.0f / 128.0f));
    float ang = p * inv;
    float sn = sinf(ang), cs = cosf(ang);
    float x1 = row[col], x2 = row[col + 64];
    float o1 = x1 * cs - x2 * sn;
    float o2 = x2 * cs + x1 * sn;
    unsigned short h1 = f2bf(o1), h2 = f2bf(o2);
    dh[dbase + d] = h1; dl[dbase + d] = f2bf(o1 - bf2f(h1));
    dh[dbase + d + 64] = h2; dl[dbase + d + 64] = f2bf(o2 - bf2f(h2));
  }
  for (int idx = tid; idx < NKV * VD; idx += 256) {
    float v = row[5120 + idx];
    size_t o = (size_t)t * (NKV * VD) + idx;
    unsigned short hh = f2bf(v);
    vh[o] = hh; vl[o] = f2bf(v - bf2f(hh));
  }
}

// ---------------------------------------------------------------------------
// Flash attention, sliding window + sink; bf16 hi/lo inputs; split-bf16 MFMA.
// ---------------------------------------------------------------------------
__global__ __launch_bounds__(256) void attn_kernel(
    const ushort_t* __restrict__ qh, const ushort_t* __restrict__ ql,
    const ushort_t* __restrict__ kh, const ushort_t* __restrict__ kl,
    const ushort_t* __restrict__ vhp, const ushort_t* __restrict__ vlp,
    const float* __restrict__ sink, const int* __restrict__ pos,
    ushort_t* __restrict__ aoh, ushort_t* __restrict__ aol)
{
  __shared__ __align__(16) ushort_t Qs[2][64][136];
  __shared__ __align__(16) ushort_t Ks[2][32][136];
  __shared__ __align__(16) ushort_t Vt[2][96][40];
  __shared__ __align__(16) ushort_t Ps[2][4][16][40];
  __shared__ int posq[64];
  __shared__ int posk[32];

  const float SCALE = 0.08838834764831843f;
  int qs = blockIdx.x * 64;
  int head = blockIdx.y;
  int kvh = head >> 2;
  int tid = threadIdx.x;
  int lane = tid & 63, wave = tid >> 6;
  int g = lane >> 4, cc = lane & 15;
  int wq0 = wave * 16;

#pragma unroll
  for (int i = 0; i < 4; ++i) {
    int c = tid + i * 256;
    int row = c >> 4, ks = (c & 15) << 3;
    size_t gofs = (size_t)(qs + row) * (NQ * HD) + head * HD + ks;
    *(u16x8*)&Qs[0][row][ks] = *(const u16x8*)(qh + gofs);
    *(u16x8*)&Qs[1][row][ks] = *(const u16x8*)(ql + gofs);
  }
  if (tid < 64) posq[tid] = pos[qs + tid];

  float m_r[4], l_r[4];
  f32x4 acc_o[6];
#pragma unroll
  for (int r = 0; r < 4; ++r) { m_r[r] = -__builtin_huge_valf(); l_r[r] = 0.f; }
#pragma unroll
  for (int n = 0; n < 6; ++n) acc_o[n] = fzero4();

  int kstart = qs - (WIN - 1);
  if (kstart < 0) kstart = 0;
  kstart &= ~31;
  int kend = qs + 63;

  for (int k0 = kstart; k0 <= kend; k0 += 32) {
    __syncthreads();
#pragma unroll
    for (int i = 0; i < 2; ++i) {
      int c = tid + i * 256;
      int row = c >> 4, ks = (c & 15) << 3;
      size_t gofs = (size_t)(k0 + row) * (NKV * HD) + kvh * HD + ks;
      *(u16x8*)&Ks[0][row][ks] = *(const u16x8*)(kh + gofs);
      *(u16x8*)&Ks[1][row][ks] = *(const u16x8*)(kl + gofs);
    }
#pragma unroll
    for (int i = 0; i < 3; ++i) {
      int qd = tid + i * 256;
      int key = qd / 24, vq = qd % 24;
      size_t gofs = (size_t)(k0 + key) * (NKV * VD) + kvh * VD + vq * 4;
      ushort4 a = *(const ushort4*)(vhp + gofs);
      ushort4 b = *(const ushort4*)(vlp + gofs);
      Vt[0][vq * 4 + 0][key] = a.x; Vt[0][vq * 4 + 1][key] = a.y;
      Vt[0][vq * 4 + 2][key] = a.z; Vt[0][vq * 4 + 3][key] = a.w;
      Vt[1][vq * 4 + 0][key] = b.x; Vt[1][vq * 4 + 1][key] = b.y;
      Vt[1][vq * 4 + 2][key] = b.z; Vt[1][vq * 4 + 3][key] = b.w;
    }
    if (tid < 32) posk[tid] = pos[k0 + tid];
    __syncthreads();

    bf16x8 aqh[4], aql[4];
#pragma unroll
    for (int kk = 0; kk < 4; ++kk) {
      aqh[kk] = *(const bf16x8*)&Qs[0][wq0 + cc][kk * 32 + g * 8];
      aql[kk] = *(const bf16x8*)&Qs[1][wq0 + cc][kk * 32 + g * 8];
    }
    f32x4 sacc[2];
    sacc[0] = fzero4(); sacc[1] = fzero4();
#pragma unroll
    for (int kb = 0; kb < 2; ++kb)
#pragma unroll
      for (int kk = 0; kk < 4; ++kk) {
        bf16x8 bh = *(const bf16x8*)&Ks[0][kb * 16 + cc][kk * 32 + g * 8];
        bf16x8 bl = *(const bf16x8*)&Ks[1][kb * 16 + cc][kk * 32 + g * 8];
        sacc[kb] = mfma16(aqh[kk], bh, sacc[kb]);
        sacc[kb] = mfma16(aqh[kk], bl, sacc[kb]);
        sacc[kb] = mfma16(aql[kk], bh, sacc[kb]);
      }

    int j0 = posk[cc], j1 = posk[16 + cc];
#pragma unroll
    for (int r = 0; r < 4; ++r) {
      int irow = posq[wq0 + g * 4 + r];
      float s0 = sacc[0][r] * SCALE;
      float s1 = sacc[1][r] * SCALE;
      bool ok0 = (j0 <= irow) && (irow - j0 < WIN);
      bool ok1 = (j1 <= irow) && (irow - j1 < WIN);
      if (!ok0) s0 = -1e30f;
      if (!ok1) s1 = -1e30f;
      float rm = fmaxf(s0, s1);
#pragma unroll
      for (int off = 1; off < 16; off <<= 1) rm = fmaxf(rm, __shfl_xor(rm, off));
      float mn = fmaxf(m_r[r], rm);
      float p0 = ok0 ? __expf(s0 - mn) : 0.f;
      float p1 = ok1 ? __expf(s1 - mn) : 0.f;
      float rs = p0 + p1;
#pragma unroll
      for (int off = 1; off < 16; off <<= 1) rs += __shfl_xor(rs, off);
      float alpha = __expf(m_r[r] - mn);
      l_r[r] = l_r[r] * alpha + rs;
      m_r[r] = mn;
#pragma unroll
      for (int n = 0; n < 6; ++n) acc_o[n][r] *= alpha;
      unsigned short p0h = f2bf(p0), p1h = f2bf(p1);
      Ps[0][wave][g * 4 + r][cc] = p0h;
      Ps[1][wave][g * 4 + r][cc] = f2bf(p0 - bf2f(p0h));
      Ps[0][wave][g * 4 + r][16 + cc] = p1h;
      Ps[1][wave][g * 4 + r][16 + cc] = f2bf(p1 - bf2f(p1h));
    }
    bf16x8 pah = *(const bf16x8*)&Ps[0][wave][cc][g * 8];
    bf16x8 pal = *(const bf16x8*)&Ps[1][wave][cc][g * 8];
#pragma unroll
    for (int n = 0; n < 6; ++n) {
      bf16x8 bh = *(const bf16x8*)&Vt[0][n * 16 + cc][g * 8];
      bf16x8 bl = *(const bf16x8*)&Vt[1][n * 16 + cc][g * 8];
      acc_o[n] = mfma16(pah, bh, acc_o[n]);
      acc_o[n] = mfma16(pah, bl, acc_o[n]);
      acc_o[n] = mfma16(pal, bh, acc_o[n]);
    }
  }

  float snk = sink[head];
#pragma unroll
  for (int r = 0; r < 4; ++r) {
    float m2 = fmaxf(m_r[r], snk);
    float alpha = __expf(m_r[r] - m2);
    float denom = l_r[r] * alpha + __expf(snk - m2);
    float inv = 1.f / denom;
    int row = qs + wq0 + g * 4 + r;
#pragma unroll
    for (int n = 0; n < 6; ++n) {
      float val = acc_o[n][r] * alpha * inv;
      size_t off = (size_t)row * (NQ * VD) + head * VD + n * 16 + cc;
      unsigned short hh = f2bf(val);
      aoh[off] = hh;
      aol[off] = f2bf(val - bf2f(hh));
    }
  }
}

// ---------------------------------------------------------------------------
__global__ __launch_bounds__(64) void router_kernel(const float* __restrict__ x2,
    const float* __restrict__ gw, float* __restrict__ topkw, int* __restrict__ topkid)
{
  int t = blockIdx.x;
  int lane = threadIdx.x;
  float acc[NE];
#pragma unroll
  for (int e = 0; e < NE; ++e) acc[e] = 0.f;
  for (int hh = lane; hh < H; hh += 64) {
    float xv = x2[(size_t)t * H + hh];
    const float* g = gw + (size_t)hh * NE;
#pragma unroll
    for (int e = 0; e < NE; ++e) acc[e] = fmaf(xv, g[e], acc[e]);
  }
#pragma unroll
  for (int e = 0; e < NE; ++e)
#pragma unroll
    for (int off = 32; off > 0; off >>= 1) acc[e] += __shfl_xor(acc[e], off);
  if (lane == 0) {
    int b1 = 0; float v1 = acc[0];
#pragma unroll
    for (int e = 1; e < NE; ++e) { if (acc[e] > v1) { v1 = acc[e]; b1 = e; } }
    int b2 = -1; float v2 = -3.4e38f;
#pragma unroll
    for (int e = 0; e < NE; ++e) { if (e != b1 && acc[e] > v2) { v2 = acc[e]; b2 = e; } }
    float e2 = __expf(v2 - v1);
    float s = 1.f + e2;
    topkw[t * 2] = 1.f / s;
    topkw[t * 2 + 1] = e2 / s;
    topkid[t * 2] = b1;
    topkid[t * 2 + 1] = b2;
  }
}

__global__ __launch_bounds__(256) void route_build_kernel(
    const int* __restrict__ topkid, int* __restrict__ idssort,
    int* __restrict__ prow, int* __restrict__ eoffs)
{
  __shared__ int cnt[NE];
  __shared__ int off[NE + 1];
  __shared__ int cur[NE];
  int tid = threadIdx.x;
  if (tid < NE) cnt[tid] = 0;
  __syncthreads();
  for (int p = tid; p < T * TOPK; p += 256) atomicAdd(&cnt[topkid[p]], 1);
  __syncthreads();
  if (tid == 0) {
    off[0] = 0;
    for (int e = 0; e < NE; ++e) off[e + 1] = off[e] + cnt[e];
  }
  __syncthreads();
  if (tid < NE) cur[tid] = off[tid];
  __syncthreads();
  for (int p = tid; p < T * TOPK; p += 256) {
    int e = topkid[p];
    int ppos = atomicAdd(&cur[e], 1);
    idssort[ppos] = p >> 1;
    prow[p] = ppos;
  }
  if (tid <= NE) eoffs[tid] = off[tid];
}

// ---------------------------------------------------------------------------
// silu(gate)*up on fused bf16 [4096][2816] (cols 0..1407 gate, 1408.. up).
// ---------------------------------------------------------------------------
__global__ __launch_bounds__(256) void silu_mul_kernel(
    const ushort_t* __restrict__ h12, ushort_t* __restrict__ oh)
{
  int id = blockIdx.x * 256 + threadIdx.x;   // 720896 total
  int r = id / 176;
  int c8 = (id % 176) * 8;
  u16x8 a = *(const u16x8*)&h12[(size_t)r * 2816 + c8];
  u16x8 b = *(const u16x8*)&h12[(size_t)r * 2816 + 1408 + c8];
  u16x8 o;
#pragma unroll
  for (int j = 0; j < 8; ++j) {
    float x = bf2f(a[j]), y = bf2f(b[j]);
    float rr = x / (1.f + __expf(-x)) * y;
    o[j] = f2bf(rr);
  }
  *(u16x8*)&oh[(size_t)r * 1408 + c8] = o;
}

__global__ __launch_bounds__(256) void combine_kernel(const float* __restrict__ h,
    const float* __restrict__ eo, const float* __restrict__ topkw,
    const int* __restrict__ prow, float* __restrict__ out)
{
  int t = blockIdx.x, tid = threadIdx.x;
  float w0 = topkw[t * 2], w1 = topkw[t * 2 + 1];
  const float4* e0 = (const float4*)(eo + (size_t)prow[t * 2] * H);
  const float4* e1 = (const float4*)(eo + (size_t)prow[t * 2 + 1] * H);
  const float4* hp = (const float4*)(h + (size_t)t * H);
  float4* op = (float4*)(out + (size_t)t * H);
#pragma unroll
  for (int i = 0; i < 4; ++i) {
    int idx = tid + i * 256;
    float4 a = hp[idx], b = e0[idx], c = e1[idx];
    float4 o;
    o.x = a.x + w0 * b.x + w1 * c.x;
    o.y = a.y + w0 * b.y + w1 * c.y;
    o.z = a.z + w0 * b.z + w1 * c.z;
    o.w = a.w + w0 * b.w + w1 * c.w;
    op[idx] = o;
  }
}

// ---------------------------------------------------------------------------
extern "C" void kernel_launch(void* const* d_in, const int* in_sizes, int n_in,
                              void* d_out, int out_size, void* d_ws, size_t ws_size,
                              hipStream_t stream) {
  const int*   pos   = (const int*)d_in[0];
  const float* hid   = (const float*)d_in[1];
  const float* rms1w = (const float*)d_in[2];
  const float* rms2w = (const float*)d_in[3];
  const float* wq    = (const float*)d_in[4];
  const float* wk    = (const float*)d_in[5];
  const float* wv    = (const float*)d_in[6];
  const float* wo    = (const float*)d_in[7];
  const float* sink  = (const float*)d_in[8];
  const float* gw    = (const float*)d_in[9];
  const float* wgate = (const float*)d_in[10];
  const float* wup   = (const float*)d_in[11];
  const float* wdown = (const float*)d_in[12];
  float* out = (float*)d_out;

  const size_t MB = 1048576ull;
  if (ws_size < 462ull * MB) return;  // visible clean fail if scratch too small

  char* ws = (char*)d_ws;
  // ---- weight region (phased reuse) ----
  ushort_t* wqkvT_h = (ushort_t*)(ws + 0 * MB);     // 46 MiB [5888][4096]
  ushort_t* wqkvT_l = (ushort_t*)(ws + 47 * MB);    // 46 MiB
  ushort_t* woT_h   = (ushort_t*)(ws + 94 * MB);    // 24 MiB [4096][3072]
  ushort_t* woT_l   = (ushort_t*)(ws + 118 * MB);   // 24 MiB
  ushort_t* wgupT   = (ushort_t*)(ws + 0 * MB);     // 176 MiB [8][2816][4096] (after WO)
  ushort_t* wdownT  = (ushort_t*)(ws + 176 * MB);   // 88 MiB [8][4096][1408]
  // ---- activations ----
  char* A0 = ws + 264 * MB;
  ushort_t* x1h = (ushort_t*)(A0 + 0 * MB);
  ushort_t* x1l = (ushort_t*)(A0 + 16 * MB);
  ushort_t* kh  = (ushort_t*)(A0 + 32 * MB);
  ushort_t* kl  = (ushort_t*)(A0 + 36 * MB);
  ushort_t* vh  = (ushort_t*)(A0 + 40 * MB);
  ushort_t* vl  = (ushort_t*)(A0 + 43 * MB);
  ushort_t* aoh = (ushort_t*)(A0 + 46 * MB);
  ushort_t* aol = (ushort_t*)(A0 + 58 * MB);
  ushort_t* qh  = (ushort_t*)(A0 + 0 * MB);         // over x1h (dead after QKV)
  ushort_t* ql  = (ushort_t*)(A0 + 16 * MB);        // over x1l
  float* eo   = (float*)(A0 + 0 * MB);              // 64 MiB over q/k/v/ao (dead)
  float* qkvf = (float*)(A0 + 70 * MB);             // 46 MiB [2048][5888]
  ushort_t* h12b = (ushort_t*)(A0 + 70 * MB);       // 22 MiB over qkvf (dead)
  ushort_t* h1h  = (ushort_t*)(A0 + 93 * MB);       // 11 MiB
  float* h   = (float*)(A0 + 116 * MB);
  float* x2  = (float*)(A0 + 148 * MB);
  ushort_t* x2h = (ushort_t*)(A0 + 180 * MB);
  char* sm = A0 + 196 * MB;
  float* topkw  = (float*)(sm);
  int*  topkid  = (int*)(sm + 16384);
  int*  prow    = (int*)(sm + 32768);
  int*  idssort = (int*)(sm + 49152);
  int*  eoffs   = (int*)(sm + 65536);

  // 0. weight conversion (qkv fused + wo split hi/lo; down hi only)
  tconv_kernel<1><<<dim3(64, 64, 1), 256, 0, stream>>>(wq, 4096, wqkvT_h, wqkvT_l, 4096, 0, 0, 0);
  tconv_kernel<1><<<dim3(16, 64, 1), 256, 0, stream>>>(wk, 1024, wqkvT_h, wqkvT_l, 4096, 4096, 0, 0);
  tconv_kernel<1><<<dim3(12, 64, 1), 256, 0, stream>>>(wv, 768, wqkvT_h, wqkvT_l, 4096, 5120, 0, 0);
  tconv_kernel<1><<<dim3(64, 48, 1), 256, 0, stream>>>(wo, 4096, woT_h, woT_l, 3072, 0, 0, 0);
  tconv_kernel<0><<<dim3(64, 22, 8), 256, 0, stream>>>(wdown, 4096, wdownT, nullptr, 1408, 0,
      1408LL * 4096, 4096LL * 1408);

  // 1. x1 = rmsnorm(hid) -> bf16 hi/lo
  rmsnorm_hl_kernel<<<T, 256, 0, stream>>>(hid, rms1w, x1h, x1l);

  // 2. fused QKV GEMM (split)
  gemm_bt<1, 0, 0, 0, 0><<<dim3(46, 16, 1), 256, 0, stream>>>(
      x1h, x1l, H, wqkvT_h, wqkvT_l, 0, qkvf, 5888, nullptr, nullptr, nullptr, T, H);

  // 3. RoPE + pack
  rope_pack_kernel<<<T, 256, 0, stream>>>(pos, qkvf, qh, ql, kh, kl, vh, vl);

  // 4. attention
  attn_kernel<<<dim3(T / 64, NQ, 1), 256, 0, stream>>>(qh, ql, kh, kl, vh, vl,
      sink, pos, aoh, aol);

  // 5. h = hid + ao @ wo (split)
  gemm_bt<1, 0, 0, 0, 1><<<dim3(32, 16, 1), 256, 0, stream>>>(
      aoh, aol, NQ * VD, woT_h, woT_l, 0, h, H, hid, nullptr, nullptr, T, NQ * VD);

  // 6. x2 = rmsnorm(h)
  rmsnorm_fh_kernel<<<T, 256, 0, stream>>>(h, rms2w, x2, x2h);

  // 7. routing
  router_kernel<<<T, 64, 0, stream>>>(x2, gw, topkw, topkid);
  route_build_kernel<<<1, 256, 0, stream>>>(topkid, idssort, prow, eoffs);

  // 8. MoE weight conversion (reuses dead qkv/wo weight region), gate+up, silu, down
  tconv_kernel<0><<<dim3(22, 64, 8), 256, 0, stream>>>(wgate, 1408, wgupT, nullptr, 4096, 0,
      4096LL * 1408, 2816LL * 4096);
  tconv_kernel<0><<<dim3(22, 64, 8), 256, 0, stream>>>(wup, 1408, wgupT, nullptr, 4096, 1408,
      4096LL * 1408, 2816LL * 4096);
  gemm_bt<0, 1, 1, 1, 0><<<dim3(22, 32, 8), 256, 0, stream>>>(
      x2h, nullptr, H, wgupT, nullptr, 2816LL * 4096, h12b, 2816, nullptr, idssort, eoffs, 0, H);
  silu_mul_kernel<<<2816, 256, 0, stream>>>(h12b, h1h);
  gemm_bt<0, 0, 1, 0, 0><<<dim3(32, 32, 8), 256, 0, stream>>>(
      h1h, nullptr, FF, wdownT, nullptr, 4096LL * 1408, eo, H, nullptr, nullptr, eoffs, 0, FF);

  // 9. out = h + combine(eo)
  combine_kernel<<<T, 256, 0, stream>>>(h, eo, topkw, prow, out);
}